// Round 2
// baseline (333.450 us; speedup 1.0000x reference)
//
#include <hip/hip_runtime.h>
#include <math.h>

#ifndef INFINITY
#define INFINITY __builtin_inff()
#endif

#define EPS 1e-6f
#define K4PI2 0.405284734569351086f  // 4 / pi^2

constexpr int B = 64;
constexpr int N = 25200;
constexpr int D = 21;
constexpr int G = 32;
constexpr int CHUNKS = 16;
constexpr int CHUNK = (N + CHUNKS - 1) / CHUNKS;  // 1575
constexpr int BLK = 256;

__device__ __forceinline__ float fastrcp(float x) {
    return __builtin_amdgcn_rcpf(x);  // v_rcp_f32, ~1 ulp — scores only feed argmax
}

__device__ __forceinline__ float softplusf(float x) {
    // log1p(exp(x)) stable: max(x,0) + log1p(exp(-|x|))
    return fmaxf(x, 0.0f) + log1pf(expf(-fabsf(x)));
}

// Full-reference-order CIoU with IEEE division (used only for the 2048 final terms).
__device__ __forceinline__ float ciou_exact(float p_cx, float p_cy, float pw, float ph,
                                            float g_cx, float g_cy, float gw, float gh) {
    float p_x1 = p_cx - pw * 0.5f, p_y1 = p_cy - ph * 0.5f;
    float p_x2 = p_cx + pw * 0.5f, p_y2 = p_cy + ph * 0.5f;
    float g_x1 = g_cx - gw * 0.5f, g_y1 = g_cy - gh * 0.5f;
    float g_x2 = g_cx + gw * 0.5f, g_y2 = g_cy + gh * 0.5f;
    float iw = fmaxf(fminf(p_x2, g_x2) - fmaxf(p_x1, g_x1), 0.0f);
    float ih = fmaxf(fminf(p_y2, g_y2) - fmaxf(p_y1, g_y1), 0.0f);
    float inter = iw * ih;
    float p_area = (p_x2 - p_x1) * (p_y2 - p_y1);
    float g_area = (g_x2 - g_x1) * (g_y2 - g_y1);
    float uni = p_area + g_area - inter;
    float iou = inter / (uni + EPS);
    float dx = p_cx - g_cx, dy = p_cy - g_cy;
    float cd = dx * dx + dy * dy;
    float ew = fmaxf(p_x2, g_x2) - fminf(p_x1, g_x1);
    float eh = fmaxf(p_y2, g_y2) - fminf(p_y1, g_y1);
    float ed = ew * ew + eh * eh;
    float dat = atanf(pw / ph) - atanf(gw / gh);
    float v = K4PI2 * (dat * dat);
    float alpha = v / (1.0f - iou + v + EPS);
    return iou - cd / (ed + EPS) - alpha * v;
}

// Phase 1: per (batch, chunk) block, per-gt argmax of CIoU over the chunk's preds.
__global__ __launch_bounds__(BLK) void k_argmax(const float* __restrict__ preds,
                                                const float* __restrict__ gt_boxes,
                                                float* __restrict__ pval,
                                                int* __restrict__ pidx) {
    __shared__ float4 gA[G];  // x1, y1, x2, y2
    __shared__ float4 gB[G];  // cx, cy, area, atan(w/h)
    __shared__ float sval[BLK / 64][G];
    __shared__ int sidx[BLK / 64][G];

    const int b = blockIdx.x / CHUNKS;
    const int chunk = blockIdx.x % CHUNKS;
    const int tid = threadIdx.x;

    if (tid < G) {
        const float* gb = gt_boxes + ((size_t)b * G + tid) * 4;
        float cx = gb[0], cy = gb[1], w = gb[2], h = gb[3];
        float x1 = cx - w * 0.5f, y1 = cy - h * 0.5f;
        float x2 = cx + w * 0.5f, y2 = cy + h * 0.5f;
        gA[tid] = make_float4(x1, y1, x2, y2);
        gB[tid] = make_float4(cx, cy, (x2 - x1) * (y2 - y1), atanf(w / h));
    }
    __syncthreads();

    float bestv[G];
    int besti[G];
#pragma unroll
    for (int g = 0; g < G; ++g) { bestv[g] = -INFINITY; besti[g] = 0x7fffffff; }

    const int n0 = chunk * CHUNK;
    const int n1 = (n0 + CHUNK < N) ? (n0 + CHUNK) : N;
    for (int n = n0 + tid; n < n1; n += BLK) {
        const float* pr = preds + ((size_t)b * N + n) * D;
        float cx = pr[0], cy = pr[1], w = pr[2], h = pr[3];
        float px1 = cx - w * 0.5f, py1 = cy - h * 0.5f;
        float px2 = cx + w * 0.5f, py2 = cy + h * 0.5f;
        float parea = (px2 - px1) * (py2 - py1);
        float pat = atanf(w / h);
#pragma unroll
        for (int g = 0; g < G; ++g) {
            float4 a = gA[g];
            float4 q = gB[g];
            float iw = fmaxf(fminf(px2, a.z) - fmaxf(px1, a.x), 0.0f);
            float ih = fmaxf(fminf(py2, a.w) - fmaxf(py1, a.y), 0.0f);
            float inter = iw * ih;
            float uni = parea + q.z - inter;
            float iou = inter * fastrcp(uni + EPS);
            float dx = cx - q.x, dy = cy - q.y;
            float cd = dx * dx + dy * dy;
            float ew = fmaxf(px2, a.z) - fminf(px1, a.x);
            float eh = fmaxf(py2, a.w) - fminf(py1, a.y);
            float ed = ew * ew + eh * eh;
            float dat = pat - q.w;
            float v = K4PI2 * (dat * dat);
            // alpha*v = v^2 / (1 - iou + v + EPS)
            float av = (v * v) * fastrcp((1.0f + EPS) + v - iou);
            float ciou = iou - cd * fastrcp(ed + EPS) - av;
            if (ciou > bestv[g]) { bestv[g] = ciou; besti[g] = n; }
        }
    }

    // wave (64-lane) argmax reduce, tie -> lower index (jnp.argmax first-occurrence)
    const int lane = tid & 63;
    const int wid = tid >> 6;
#pragma unroll
    for (int g = 0; g < G; ++g) {
        float v = bestv[g];
        int i = besti[g];
#pragma unroll
        for (int off = 32; off > 0; off >>= 1) {
            float ov = __shfl_down(v, off);
            int oi = __shfl_down(i, off);
            if (ov > v || (ov == v && oi < i)) { v = ov; i = oi; }
        }
        if (lane == 0) { sval[wid][g] = v; sidx[wid][g] = i; }
    }
    __syncthreads();

    if (tid < G) {
        float v = sval[0][tid];
        int i = sidx[0][tid];
#pragma unroll
        for (int w = 1; w < BLK / 64; ++w) {
            float ov = sval[w][tid];
            int oi = sidx[w][tid];
            if (ov > v || (ov == v && oi < i)) { v = ov; i = oi; }
        }
        size_t o = ((size_t)b * G + tid) * CHUNKS + chunk;
        pval[o] = v;
        pidx[o] = i;
    }
}

// Phase 2: reduce chunk partials, gather matched preds, per-batch partial loss.
__global__ __launch_bounds__(64) void k_loss(const float* __restrict__ preds,
                                             const float* __restrict__ gt_boxes,
                                             const int* __restrict__ gt_cls,
                                             const float* __restrict__ pval,
                                             const int* __restrict__ pidx,
                                             float* __restrict__ partial) {
    const int b = blockIdx.x;
    const int tid = threadIdx.x;
    float contrib = 0.0f;
    if (tid < G) {
        const int g = tid;
        size_t base = ((size_t)b * G + g) * CHUNKS;
        float v = pval[base];
        int i = pidx[base];
#pragma unroll
        for (int c = 1; c < CHUNKS; ++c) {
            float ov = pval[base + c];
            int oi = pidx[base + c];
            if (ov > v || (ov == v && oi < i)) { v = ov; i = oi; }
        }
        const float* pr = preds + ((size_t)b * N + i) * D;
        const float* gb = gt_boxes + ((size_t)b * G + g) * 4;
        float ciou = ciou_exact(pr[0], pr[1], pr[2], pr[3], gb[0], gb[1], gb[2], gb[3]);
        float loss_box = 1.0f - ciou;
        float loss_obj = softplusf(-pr[4]);
        int cls = gt_cls[b * G + g];
        float loss_cls = softplusf(-pr[5 + cls]);
        contrib = 5.0f * loss_box + loss_obj + loss_cls;
    }
#pragma unroll
    for (int off = 32; off > 0; off >>= 1) contrib += __shfl_down(contrib, off);
    if (tid == 0) partial[b] = contrib;
}

// Phase 3: sum 64 per-batch partials into the scalar output.
__global__ __launch_bounds__(64) void k_final(const float* __restrict__ partial,
                                              float* __restrict__ out) {
    float v = partial[threadIdx.x];
#pragma unroll
    for (int off = 32; off > 0; off >>= 1) v += __shfl_down(v, off);
    if (threadIdx.x == 0) out[0] = v;
}

extern "C" void kernel_launch(void* const* d_in, const int* in_sizes, int n_in,
                              void* d_out, int out_size, void* d_ws, size_t ws_size,
                              hipStream_t stream) {
    const float* preds = (const float*)d_in[0];
    const float* gt_boxes = (const float*)d_in[1];
    const int* gt_cls = (const int*)d_in[2];
    float* out = (float*)d_out;

    float* pval = (float*)d_ws;                                           // B*G*CHUNKS f32
    int* pidx = (int*)((char*)d_ws + sizeof(float) * (size_t)B * G * CHUNKS);
    float* partial = (float*)((char*)d_ws + 2 * sizeof(float) * (size_t)B * G * CHUNKS);

    k_argmax<<<B * CHUNKS, BLK, 0, stream>>>(preds, gt_boxes, pval, pidx);
    k_loss<<<B, 64, 0, stream>>>(preds, gt_boxes, gt_cls, pval, pidx, partial);
    k_final<<<1, 64, 0, stream>>>(partial, out);
}